// Round 5
// baseline (214.758 us; speedup 1.0000x reference)
//
#include <hip/hip_runtime.h>
#include <hip/hip_bf16.h>

// Problem constants: B=8, S=2048, E=768, HEAD=128
#define BB 8
#define SS 2048
#define EE 768
#define HH 128
#define MM (BB*SS)     // 16384
#define NQT 32         // 64-row q-tiles per batch
#define NCH 144        // chunks per batch: sum_{qt} ceil((qt+1)/4)

typedef __attribute__((ext_vector_type(8))) short bf16x8;
typedef __attribute__((ext_vector_type(8))) unsigned short ushort8;
typedef __attribute__((ext_vector_type(4))) float f32x4;

__device__ __forceinline__ unsigned short f2bf(float x) {
    unsigned int u = __float_as_uint(x);
    u += 0x7fff + ((u >> 16) & 1);   // RNE
    return (unsigned short)(u >> 16);
}
__device__ __forceinline__ float bf2f(unsigned short h) {
    return __uint_as_float(((unsigned int)h) << 16);
}
// async global->LDS, 16B per lane; LDS dest = wave-uniform base + lane*16
__device__ __forceinline__ void gld16(const unsigned short* g, unsigned short* l) {
    __builtin_amdgcn_global_load_lds(
        (const __attribute__((address_space(1))) unsigned int*)g,
        (__attribute__((address_space(3))) unsigned int*)l, 16, 0, 0);
}

// ---------------------------------------------------------------------------
// cvt: Xb = bf16(X * mask)  [16384][768];  Wb = bf16([Wq;Wk;Wv]) [384][768]
// grid 1536 (X, grid-stride x8) + 288 (W), 256 thr. Pure 32-bit indexing.
// ---------------------------------------------------------------------------
__global__ __launch_bounds__(256)
void cvt(const float* __restrict__ X, const float* __restrict__ mask,
         const float* __restrict__ Wq, const float* __restrict__ Wk,
         const float* __restrict__ Wv,
         unsigned short* __restrict__ Xb, unsigned short* __restrict__ Wb)
{
    const int bid = blockIdx.x;
    if (bid < 1536) {
        int base = bid * 256 + threadIdx.x;          // float4 index
#pragma unroll
        for (int it = 0; it < 8; it++) {
            int idx = base + it * 393216;            // < 3145728
            int row = idx / 192;                     // 192 float4 per row
            int i4  = idx * 4;
            float mk = mask[row];
            float4 v = *(const float4*)(X + i4);
            ushort4 o;
            o.x = f2bf(v.x * mk); o.y = f2bf(v.y * mk);
            o.z = f2bf(v.z * mk); o.w = f2bf(v.w * mk);
            *(ushort4*)(Xb + i4) = o;
        }
    } else {
        int i4 = ((bid - 1536) * 256 + threadIdx.x) * 4;   // < 294912
        const float* src; int off;
        if (i4 < 98304)       { src = Wq; off = i4; }
        else if (i4 < 196608) { src = Wk; off = i4 - 98304; }
        else                  { src = Wv; off = i4 - 196608; }
        float4 v = *(const float4*)(src + off);
        ushort4 o;
        o.x = f2bf(v.x); o.y = f2bf(v.y); o.z = f2bf(v.z); o.w = f2bf(v.w);
        *(ushort4*)(Wb + i4) = o;
    }
}

// ---------------------------------------------------------------------------
// QKV GEMM: 64M x 128N tile, BK=64, grid (256, 3) = 3 blocks/CU.
// global_load_lds(16B) staging, xor-swizzled unpadded LDS.
// Waves split N: wave w owns cols [w*32, w*32+32). acc 4x2 per wave.
// mat 2 (V): LDS-bounce transpose -> coalesced Vt[h][token] stores.
// ---------------------------------------------------------------------------
__global__ __launch_bounds__(256, 3)
void qkv_gemm(const unsigned short* __restrict__ Xb, const unsigned short* __restrict__ Wb,
              unsigned short* __restrict__ Q, unsigned short* __restrict__ K,
              unsigned short* __restrict__ Vt)
{
    const int m0  = blockIdx.x * 64;
    const int mat = blockIdx.y;
    const int n0g = mat * 128;               // row offset into Wb [384][768]

    __shared__ __align__(16) unsigned short SM[12288];   // As 8KB | Bs 16KB
    unsigned short* As = SM;                 // [64 rows][8 chunks] swizzled
    unsigned short* Bs = SM + 4096;          // [128 rows][8 chunks] swizzled

    const int t = threadIdx.x, lane = t & 63;
    const int quad = lane >> 4, l16 = lane & 15;
    const int wave = t >> 6;
    const int wn = wave * 32;
    const int wub = (t & 192) * 8;           // wave-uniform base (shorts)

    f32x4 acc[4][2];
#pragma unroll
    for (int i = 0; i < 4; i++)
#pragma unroll
        for (int j = 0; j < 2; j++) acc[i][j] = (f32x4)0.0f;

    for (int k0 = 0; k0 < EE; k0 += 64) {
        __syncthreads();
        // A: 64 rows x 8 chunks (2 passes)
#pragma unroll
        for (int i = 0; i < 2; i++) {
            int cg = i * 256 + t;
            int row = cg >> 3, slot = cg & 7;
            int cc = slot ^ (row & 7);
            gld16(Xb + (size_t)(m0 + row) * EE + k0 + cc * 8, As + i * 2048 + wub);
        }
        // B: 128 rows x 8 chunks (4 passes)
#pragma unroll
        for (int i = 0; i < 4; i++) {
            int cg = i * 256 + t;
            int row = cg >> 3, slot = cg & 7;
            int cc = slot ^ (row & 7);
            gld16(Wb + (size_t)(n0g + row) * EE + k0 + cc * 8, Bs + i * 2048 + wub);
        }
        __syncthreads();
#pragma unroll
        for (int kk = 0; kk < 2; kk++) {
            bf16x8 a[4], b[2];
#pragma unroll
            for (int i = 0; i < 4; i++) {
                int row = i * 16 + l16;
                a[i] = *(const bf16x8*)&As[row * 64 + (((kk * 4 + quad) ^ (l16 & 7)) << 3)];
            }
#pragma unroll
            for (int j = 0; j < 2; j++) {
                int row = wn + j * 16 + l16;
                b[j] = *(const bf16x8*)&Bs[row * 64 + (((kk * 4 + quad) ^ (l16 & 7)) << 3)];
            }
#pragma unroll
            for (int i = 0; i < 4; i++)
#pragma unroll
                for (int j = 0; j < 2; j++)
                    acc[i][j] = __builtin_amdgcn_mfma_f32_16x16x32_bf16(a[i], b[j], acc[i][j], 0, 0, 0);
        }
    }

    if (mat < 2) {
        unsigned short* dst = (mat == 0) ? Q : K;
#pragma unroll
        for (int i = 0; i < 4; i++)
#pragma unroll
            for (int r = 0; r < 4; r++) {
                int m = m0 + i * 16 + quad * 4 + r;
#pragma unroll
                for (int j = 0; j < 2; j++)
                    dst[(size_t)m * HH + wn + j * 16 + l16] = f2bf(acc[i][j][r]);
            }
    } else {
        // transpose 64(tok) x 128(h) through LDS: SM[h][tok], slot = cc^(h&7)
        __syncthreads();
#pragma unroll
        for (int i = 0; i < 4; i++)
#pragma unroll
            for (int r = 0; r < 4; r++) {
                int tok = i * 16 + quad * 4 + r;
                int cc = tok >> 3, w = tok & 7;
#pragma unroll
                for (int j = 0; j < 2; j++) {
                    int h = wn + j * 16 + l16;
                    SM[h * 64 + ((cc ^ (h & 7)) << 3) + w] = f2bf(acc[i][j][r]);
                }
            }
        __syncthreads();
        const int bidx = m0 >> 11, mloc = m0 & 2047;
#pragma unroll
        for (int i = 0; i < 4; i++) {
            int cg = i * 256 + t;
            int h = cg >> 3, cc = cg & 7;
            ulonglong2 v = *(const ulonglong2*)&SM[h * 64 + ((cc ^ (h & 7)) << 3)];
            *(ulonglong2*)&Vt[((size_t)bidx * HH + h) * SS + mloc + cc * 8] = v;
        }
    }
}

// ---------------------------------------------------------------------------
// Flash attention, balanced chunked k-split. grid (8=batch, 144=chunk):
// linear id % 8 == batch -> each XCD's L2 caches one batch's K/V (1 MB).
// K staged in LDS (16KB); V fragments loaded DIRECT from global (Vt layout
// makes the PV B-fragment a natural 16B-per-lane load) -> less barrier-drained
// staging. LDS 24KB -> 5 blocks/CU. Po stored in permuted [row][l16][j]
// layout as 16B vector stores (full-line writes, no write amplification).
// ---------------------------------------------------------------------------
__global__ __launch_bounds__(256, 5)
void attn(const unsigned short* __restrict__ Q, const unsigned short* __restrict__ K,
          const unsigned short* __restrict__ Vt,
          unsigned short* __restrict__ Po, float* __restrict__ Pm, float* __restrict__ Pl)
{
    const int b = blockIdx.x;
    const int c = blockIdx.y;
    // decode chunk id -> (qt, ch): cumulative chunks before group g = 2g(g+1)
    int g = (int)((__builtin_sqrtf(2.0f * c + 1.0f) - 1.0f) * 0.5f);
    while (2 * (g + 1) * (g + 2) <= c) g++;
    while (2 * g * (g + 1) > c) g--;
    const int idx = c - 2 * g * (g + 1);
    const int qt = 4 * g + idx / (g + 1);
    const int ch = idx % (g + 1);
    const int q0 = qt * 64;
    const int kt0 = ch * 4;
    const int kt1 = min(kt0 + 4, qt + 1);

    const int t = threadIdx.x, lane = t & 63;
    const int wave = t >> 6, quad = lane >> 4, l16 = lane & 15;
    const int wub = (t & 192) * 8;

    __shared__ __align__(16) unsigned short Ks[64 * 128];   // [tok][d] slot=cc^(tok&15)
    __shared__ __align__(16) unsigned short Ps[4][16 * 64]; // per-wave [row][tok] slot=cc^(row&7)

    bf16x8 qf[4];
    {
        const unsigned short* qrow = Q + (size_t)(b * SS + q0 + wave * 16 + l16) * HH;
#pragma unroll
        for (int dd = 0; dd < 4; dd++)
            qf[dd] = *(const bf16x8*)(qrow + dd * 32 + quad * 8);
    }
    const unsigned short* Vb = Vt + (size_t)b * HH * SS;

    f32x4 o[8];
#pragma unroll
    for (int j = 0; j < 8; j++) o[j] = (f32x4)0.0f;
    f32x4 o9 = (f32x4)0.0f;                  // row-sum accumulator (l)
    float mrow[4];
#pragma unroll
    for (int r = 0; r < 4; r++) mrow[r] = -1e30f;

    const float sscale = 0.08838834764831845f * 1.4426950408889634f;  // 1/sqrt(128)*log2e

    bf16x8 ones;
    {
        short e = (l16 == 0) ? (short)0x3F80 : (short)0;
        ones = (bf16x8){e, e, e, e, e, e, e, e};
    }

    for (int kt = kt0; kt < kt1; kt++) {
        const int k0 = kt * 64;
        __syncthreads();
        // stage K-tile: 64 rows x 16 chunks (4 passes)
#pragma unroll
        for (int i = 0; i < 4; i++) {
            int cg = i * 256 + t;
            int row = cg >> 4, slot = cg & 15;
            int cc = slot ^ (row & 15);
            gld16(K + (size_t)(b * SS + k0 + row) * HH + cc * 8, Ks + i * 2048 + wub);
        }
        __syncthreads();

        // S = Q K^T
        f32x4 s[4];
#pragma unroll
        for (int ct = 0; ct < 4; ct++) s[ct] = (f32x4)0.0f;
#pragma unroll
        for (int dd = 0; dd < 4; dd++) {
#pragma unroll
            for (int ct = 0; ct < 4; ct++) {
                bf16x8 kfr = *(const bf16x8*)&Ks[(ct * 16 + l16) * 128 + (((dd * 4 + quad) ^ l16) << 3)];
                s[ct] = __builtin_amdgcn_mfma_f32_16x16x32_bf16(qf[dd], kfr, s[ct], 0, 0, 0);
            }
        }

        const bool diag = (kt == qt);
        float sv[4][4];
#pragma unroll
        for (int ct = 0; ct < 4; ct++) {
            int col = k0 + ct * 16 + l16;
#pragma unroll
            for (int r = 0; r < 4; r++) {
                float v = s[ct][r] * sscale;
                if (diag) {
                    int row = q0 + wave * 16 + quad * 4 + r;
                    if (col > row) v = -1e30f;
                }
                sv[ct][r] = v;
            }
        }

        float alpha[4];
#pragma unroll
        for (int r = 0; r < 4; r++) {
            float v = fmaxf(fmaxf(sv[0][r], sv[1][r]), fmaxf(sv[2][r], sv[3][r]));
            v = fmaxf(v, __shfl_xor(v, 1));
            v = fmaxf(v, __shfl_xor(v, 2));
            v = fmaxf(v, __shfl_xor(v, 4));
            v = fmaxf(v, __shfl_xor(v, 8));
            float mnew = fmaxf(mrow[r], v);
            alpha[r] = exp2f(mrow[r] - mnew);
            mrow[r]  = mnew;
        }
        // P -> wave-private swizzled LDS
#pragma unroll
        for (int ct = 0; ct < 4; ct++) {
#pragma unroll
            for (int r = 0; r < 4; r++) {
                float p = exp2f(sv[ct][r] - mrow[r]);
                int row = quad * 4 + r, col = ct * 16 + l16;
                int cc = col >> 3;
                Ps[wave][row * 64 + (((cc ^ (row & 7)) << 3) | (col & 7))] = f2bf(p);
            }
        }
#pragma unroll
        for (int j = 0; j < 8; j++)
#pragma unroll
            for (int r = 0; r < 4; r++) o[j][r] *= alpha[r];
#pragma unroll
        for (int r = 0; r < 4; r++) o9[r] *= alpha[r];

        // PV: P from wave-private LDS; V fragments DIRECT from global.
        // B-frag for j-tile: V[h = j*16+l16][tok = k0 + kk*32 + quad*8 ..+8]
#pragma unroll
        for (int kk = 0; kk < 2; kk++) {
            bf16x8 pf = *(const bf16x8*)&Ps[wave][l16 * 64 + (((kk * 4 + quad) ^ (l16 & 7)) << 3)];
#pragma unroll
            for (int j = 0; j < 8; j++) {
                bf16x8 vf = *(const bf16x8*)(Vb + (size_t)(j * 16 + l16) * SS + k0 + kk * 32 + quad * 8);
                o[j] = __builtin_amdgcn_mfma_f32_16x16x32_bf16(pf, vf, o[j], 0, 0, 0);
            }
            o9 = __builtin_amdgcn_mfma_f32_16x16x32_bf16(pf, ones, o9, 0, 0, 0);
        }
    }

    // store partials: Po permuted layout [row][l16][j] -> 16B/lane stores
    const size_t pidx = (size_t)b * NCH + c;
    const size_t pobase = pidx * (64 * 128);
    const size_t mbase  = pidx * 64;
#pragma unroll
    for (int r = 0; r < 4; r++) {
        int row = wave * 16 + quad * 4 + r;
        if (l16 == 0) { Pm[mbase + row] = mrow[r]; Pl[mbase + row] = o9[r]; }
        ushort8 val;
#pragma unroll
        for (int j = 0; j < 8; j++) val[j] = f2bf(o[j][r]);
        *(ushort8*)&Po[pobase + (size_t)row * 128 + l16 * 8] = val;
    }
}

// ---------------------------------------------------------------------------
// Combine n_ch(qt) partials per (b,qt). grid (32, 8, 4), 16 q-rows per block.
// Reads Po in the permuted layout (coalesced), un-permutes on Out write.
// ---------------------------------------------------------------------------
__global__ __launch_bounds__(256)
void combine(const unsigned short* __restrict__ Po, const float* __restrict__ Pm,
             const float* __restrict__ Pl, float* __restrict__ Out)
{
    const int qt = blockIdx.x, b = blockIdx.y, qr = blockIdx.z;  // 16-row quarter
    const int g = qt >> 2;
    const int n_ch = g + 1;
    const int cbase = 2 * g * (g + 1) + (qt - 4 * g) * (g + 1);
    const size_t p0 = (size_t)b * NCH + cbase;
    const int t = threadIdx.x;
    const int p = t & 127;                    // permuted col: p = l16*8 + j
    const int col = (p & 7) * 16 + (p >> 3);  // logical head-dim col
    const int rh = t >> 7;

    __shared__ float sm[8][16], sl[8][16], sw[8][16];
    __shared__ float sinv[16];

    if (t < 128) {
        int s = t >> 4, row = t & 15;
        float mv = -1e30f, lv = 0.0f;
        if (s < n_ch) {
            mv = Pm[(p0 + s) * 64 + qr * 16 + row];
            lv = Pl[(p0 + s) * 64 + qr * 16 + row];
        }
        sm[s][row] = mv; sl[s][row] = lv;
    }
    __syncthreads();
    if (t < 16) {
        int row = t;
        float ms = sm[0][row];
#pragma unroll
        for (int s = 1; s < 8; s++) ms = fmaxf(ms, sm[s][row]);
        float l = 0.0f;
#pragma unroll
        for (int s = 0; s < 8; s++) {
            float w = (sm[s][row] > -1e29f) ? exp2f(sm[s][row] - ms) : 0.0f;
            sw[s][row] = w;
            l += w * sl[s][row];
        }
        sinv[row] = 1.0f / l;
    }
    __syncthreads();

#pragma unroll
    for (int pass = 0; pass < 8; pass++) {
        int row = pass * 2 + rh;          // 0..15 local
        int grow = qr * 16 + row;         // 0..63 within q-tile
        float acc = 0.0f;
#pragma unroll
        for (int s = 0; s < 8; s++) {
            int ss = (s < n_ch) ? s : 0;  // keep load valid; weight is 0
            acc += sw[s][row] * bf2f(Po[(p0 + ss) * 8192 + (size_t)grow * 128 + p]);
        }
        Out[((size_t)b * SS + qt * 64 + grow) * HH + col] = acc * sinv[row];
    }
}

extern "C" void kernel_launch(void* const* d_in, const int* in_sizes, int n_in,
                              void* d_out, int out_size, void* d_ws, size_t ws_size,
                              hipStream_t stream) {
    const float* X    = (const float*)d_in[0];
    const float* mask = (const float*)d_in[1];
    const float* Wq   = (const float*)d_in[2];
    const float* Wk   = (const float*)d_in[3];
    const float* Wv   = (const float*)d_in[4];

    char* ws = (char*)d_ws;
    // region A: Xb (25.2 MB) consumed by qkv_gemm, then reused as Po (18.9 MB)
    unsigned short* Xb = (unsigned short*)ws;
    unsigned short* Po = (unsigned short*)ws;
    ws += (size_t)MM * EE * 2;                                   // 25.17 MB
    unsigned short* Wb = (unsigned short*)ws; ws += (size_t)384 * EE * 2;
    unsigned short* Q  = (unsigned short*)ws; ws += (size_t)MM * HH * 2;
    unsigned short* Kb = (unsigned short*)ws; ws += (size_t)MM * HH * 2;
    unsigned short* Vt = (unsigned short*)ws; ws += (size_t)MM * HH * 2;
    float* Pm = (float*)ws; ws += (size_t)BB * NCH * 64 * 4;
    float* Pl = (float*)ws;

    cvt<<<1536 + 288, 256, 0, stream>>>(X, mask, Wq, Wk, Wv, Xb, Wb);
    qkv_gemm<<<dim3(MM / 64, 3), 256, 0, stream>>>(Xb, Wb, Q, Kb, Vt);
    attn<<<dim3(BB, NCH), 256, 0, stream>>>(Q, Kb, Vt, Po, Pm, Pl);
    combine<<<dim3(NQT, BB, 4), 256, 0, stream>>>(Po, Pm, Pl, (float*)d_out);
}

// Round 6
// 148.695 us; speedup vs baseline: 1.4443x; 1.4443x over previous
//
#include <hip/hip_runtime.h>
#include <hip/hip_bf16.h>

// Problem constants: B=8, S=2048, E=768, HEAD=128
#define BB 8
#define SS 2048
#define EE 768
#define HH 128
#define MM (BB*SS)     // 16384
#define NQT 32         // 64-row q-tiles per batch
#define NCH 144        // chunks per batch: sum_{qt} ceil((qt+1)/4)

typedef __attribute__((ext_vector_type(8))) short bf16x8;
typedef __attribute__((ext_vector_type(8))) unsigned short ushort8;
typedef __attribute__((ext_vector_type(4))) float f32x4;

__device__ __forceinline__ unsigned short f2bf(float x) {
    unsigned int u = __float_as_uint(x);
    u += 0x7fff + ((u >> 16) & 1);   // RNE
    return (unsigned short)(u >> 16);
}
__device__ __forceinline__ float bf2f(unsigned short h) {
    return __uint_as_float(((unsigned int)h) << 16);
}
// async global->LDS, 16B per lane; LDS dest = wave-uniform base + lane*16
__device__ __forceinline__ void gld16(const unsigned short* g, unsigned short* l) {
    __builtin_amdgcn_global_load_lds(
        (const __attribute__((address_space(1))) unsigned int*)g,
        (__attribute__((address_space(3))) unsigned int*)l, 16, 0, 0);
}

// ---------------------------------------------------------------------------
// cvt: Xb = bf16(X * mask)  [16384][768];  Wb = bf16([Wq;Wk;Wv]) [384][768]
// grid 1536 (X, grid-stride x8) + 288 (W), 256 thr. Pure 32-bit indexing.
// ---------------------------------------------------------------------------
__global__ __launch_bounds__(256)
void cvt(const float* __restrict__ X, const float* __restrict__ mask,
         const float* __restrict__ Wq, const float* __restrict__ Wk,
         const float* __restrict__ Wv,
         unsigned short* __restrict__ Xb, unsigned short* __restrict__ Wb)
{
    const int bid = blockIdx.x;
    if (bid < 1536) {
        int base = bid * 256 + threadIdx.x;          // float4 index
#pragma unroll
        for (int it = 0; it < 8; it++) {
            int idx = base + it * 393216;            // < 3145728
            int row = idx / 192;                     // 192 float4 per row
            int i4  = idx * 4;
            float mk = mask[row];
            float4 v = *(const float4*)(X + i4);
            ushort4 o;
            o.x = f2bf(v.x * mk); o.y = f2bf(v.y * mk);
            o.z = f2bf(v.z * mk); o.w = f2bf(v.w * mk);
            *(ushort4*)(Xb + i4) = o;
        }
    } else {
        int i4 = ((bid - 1536) * 256 + threadIdx.x) * 4;   // < 294912
        const float* src; int off;
        if (i4 < 98304)       { src = Wq; off = i4; }
        else if (i4 < 196608) { src = Wk; off = i4 - 98304; }
        else                  { src = Wv; off = i4 - 196608; }
        float4 v = *(const float4*)(src + off);
        ushort4 o;
        o.x = f2bf(v.x); o.y = f2bf(v.y); o.z = f2bf(v.z); o.w = f2bf(v.w);
        *(ushort4*)(Wb + i4) = o;
    }
}

// ---------------------------------------------------------------------------
// QKV GEMM: 64M x 128N tile, BK=64, grid (3=mat FASTEST, 256) = 3 blocks/CU.
// mat-fastest dispatch: the 3 blocks sharing an A-tile are adjacent -> L2
// serves 2 of 3 Xb reads. global_load_lds staging, xor-swizzled LDS.
// mat 2 (V): LDS-bounce transpose -> coalesced Vt[h][token] stores.
// ---------------------------------------------------------------------------
__global__ __launch_bounds__(256, 3)
void qkv_gemm(const unsigned short* __restrict__ Xb, const unsigned short* __restrict__ Wb,
              unsigned short* __restrict__ Q, unsigned short* __restrict__ K,
              unsigned short* __restrict__ Vt)
{
    const int mat = blockIdx.x;
    const int m0  = blockIdx.y * 64;
    const int n0g = mat * 128;               // row offset into Wb [384][768]

    __shared__ __align__(16) unsigned short SM[12288];   // As 8KB | Bs 16KB
    unsigned short* As = SM;                 // [64 rows][8 chunks] swizzled
    unsigned short* Bs = SM + 4096;          // [128 rows][8 chunks] swizzled

    const int t = threadIdx.x, lane = t & 63;
    const int quad = lane >> 4, l16 = lane & 15;
    const int wave = t >> 6;
    const int wn = wave * 32;
    const int wub = (t & 192) * 8;           // wave-uniform base (shorts)

    f32x4 acc[4][2];
#pragma unroll
    for (int i = 0; i < 4; i++)
#pragma unroll
        for (int j = 0; j < 2; j++) acc[i][j] = (f32x4)0.0f;

    for (int k0 = 0; k0 < EE; k0 += 64) {
        __syncthreads();
        // A: 64 rows x 8 chunks (2 passes)
#pragma unroll
        for (int i = 0; i < 2; i++) {
            int cg = i * 256 + t;
            int row = cg >> 3, slot = cg & 7;
            int cc = slot ^ (row & 7);
            gld16(Xb + (size_t)(m0 + row) * EE + k0 + cc * 8, As + i * 2048 + wub);
        }
        // B: 128 rows x 8 chunks (4 passes)
#pragma unroll
        for (int i = 0; i < 4; i++) {
            int cg = i * 256 + t;
            int row = cg >> 3, slot = cg & 7;
            int cc = slot ^ (row & 7);
            gld16(Wb + (size_t)(n0g + row) * EE + k0 + cc * 8, Bs + i * 2048 + wub);
        }
        __syncthreads();
#pragma unroll
        for (int kk = 0; kk < 2; kk++) {
            bf16x8 a[4], b[2];
#pragma unroll
            for (int i = 0; i < 4; i++) {
                int row = i * 16 + l16;
                a[i] = *(const bf16x8*)&As[row * 64 + (((kk * 4 + quad) ^ (l16 & 7)) << 3)];
            }
#pragma unroll
            for (int j = 0; j < 2; j++) {
                int row = wn + j * 16 + l16;
                b[j] = *(const bf16x8*)&Bs[row * 64 + (((kk * 4 + quad) ^ (l16 & 7)) << 3)];
            }
#pragma unroll
            for (int i = 0; i < 4; i++)
#pragma unroll
                for (int j = 0; j < 2; j++)
                    acc[i][j] = __builtin_amdgcn_mfma_f32_16x16x32_bf16(a[i], b[j], acc[i][j], 0, 0, 0);
        }
    }

    if (mat < 2) {
        unsigned short* dst = (mat == 0) ? Q : K;
#pragma unroll
        for (int i = 0; i < 4; i++)
#pragma unroll
            for (int r = 0; r < 4; r++) {
                int m = m0 + i * 16 + quad * 4 + r;
#pragma unroll
                for (int j = 0; j < 2; j++)
                    dst[(size_t)m * HH + wn + j * 16 + l16] = f2bf(acc[i][j][r]);
            }
    } else {
        // transpose 64(tok) x 128(h) through LDS: SM[h][tok], slot = cc^(h&7)
        __syncthreads();
#pragma unroll
        for (int i = 0; i < 4; i++)
#pragma unroll
            for (int r = 0; r < 4; r++) {
                int tok = i * 16 + quad * 4 + r;
                int cc = tok >> 3, w = tok & 7;
#pragma unroll
                for (int j = 0; j < 2; j++) {
                    int h = wn + j * 16 + l16;
                    SM[h * 64 + ((cc ^ (h & 7)) << 3) + w] = f2bf(acc[i][j][r]);
                }
            }
        __syncthreads();
        const int bidx = m0 >> 11, mloc = m0 & 2047;
#pragma unroll
        for (int i = 0; i < 4; i++) {
            int cg = i * 256 + t;
            int h = cg >> 3, cc = cg & 7;
            ulonglong2 v = *(const ulonglong2*)&SM[h * 64 + ((cc ^ (h & 7)) << 3)];
            *(ulonglong2*)&Vt[((size_t)bidx * HH + h) * SS + mloc + cc * 8] = v;
        }
    }
}

// ---------------------------------------------------------------------------
// Flash attention — R2's measured-best structure (vector-load staging, padded
// LDS: Ks 136 / Vs 72 / Ps 72) + balanced contiguous chunks (<=4 k-tiles) +
// full-line permuted 16B Po stores (no partial-line write amplification).
// LDS 45 KB -> 3 blocks/CU. grid (144, 8), block 256 (4 waves x 16 q-rows).
// ---------------------------------------------------------------------------
__global__ __launch_bounds__(256, 3)
void attn(const unsigned short* __restrict__ Q, const unsigned short* __restrict__ K,
          const unsigned short* __restrict__ Vt,
          unsigned short* __restrict__ Po, float* __restrict__ Pm, float* __restrict__ Pl)
{
    const int c = blockIdx.x, b = blockIdx.y;
    // decode chunk id -> (qt, ch): cumulative chunks before group g = 2g(g+1)
    int g = (int)((__builtin_sqrtf(2.0f * c + 1.0f) - 1.0f) * 0.5f);
    while (2 * (g + 1) * (g + 2) <= c) g++;
    while (2 * g * (g + 1) > c) g--;
    const int idx = c - 2 * g * (g + 1);
    const int qt = 4 * g + idx / (g + 1);
    const int ch = idx % (g + 1);
    const int q0 = qt * 64;
    const int kt0 = ch * 4;
    const int kt1 = min(kt0 + 4, qt + 1);

    const int t = threadIdx.x, lane = t & 63;
    const int wave = t >> 6, quad = lane >> 4, l16 = lane & 15;

    __shared__ __align__(16) unsigned short Ks[64 * 136];   // [tok][d]
    __shared__ __align__(16) unsigned short Vs[128 * 72];   // [h][tok]
    __shared__ __align__(16) unsigned short Ps[4][16 * 72]; // per-wave [row][tok]

    bf16x8 qf[4];
    {
        const unsigned short* qrow = Q + (size_t)(b * SS + q0 + wave * 16 + l16) * HH;
#pragma unroll
        for (int dd = 0; dd < 4; dd++)
            qf[dd] = *(const bf16x8*)(qrow + dd * 32 + quad * 8);
    }

    f32x4 o[8];
#pragma unroll
    for (int j = 0; j < 8; j++) o[j] = (f32x4)0.0f;
    f32x4 o9 = (f32x4)0.0f;                  // row-sum accumulator (l)
    float mrow[4];
#pragma unroll
    for (int r = 0; r < 4; r++) mrow[r] = -1e30f;

    const float sscale = 0.08838834764831845f * 1.4426950408889634f;  // 1/sqrt(128)*log2e

    bf16x8 ones;
    {
        short e = (l16 == 0) ? (short)0x3F80 : (short)0;
        ones = (bf16x8){e, e, e, e, e, e, e, e};
    }

    for (int kt = kt0; kt < kt1; kt++) {
        const int k0 = kt * 64;
        __syncthreads();
        // stage K-tile 64x128 (vector loads -> padded LDS)
#pragma unroll
        for (int it = 0; it < 4; it++) {
            int flat = it * 256 + t;
            int row = flat >> 4, c8 = (flat & 15) * 8;
            *(ulonglong2*)&Ks[row * 136 + c8] =
                *(const ulonglong2*)(K + (size_t)(b * SS + k0 + row) * HH + c8);
        }
        // stage V^T-tile 128x64
#pragma unroll
        for (int it = 0; it < 4; it++) {
            int flat = it * 256 + t;
            int row = flat >> 3, c8 = (flat & 7) * 8;
            *(ulonglong2*)&Vs[row * 72 + c8] =
                *(const ulonglong2*)(Vt + ((size_t)b * HH + row) * SS + k0 + c8);
        }
        __syncthreads();

        // S = Q K^T
        f32x4 s[4];
#pragma unroll
        for (int ct = 0; ct < 4; ct++) s[ct] = (f32x4)0.0f;
#pragma unroll
        for (int dd = 0; dd < 4; dd++) {
#pragma unroll
            for (int ct = 0; ct < 4; ct++) {
                bf16x8 kfr = *(const bf16x8*)&Ks[(ct * 16 + l16) * 136 + dd * 32 + quad * 8];
                s[ct] = __builtin_amdgcn_mfma_f32_16x16x32_bf16(qf[dd], kfr, s[ct], 0, 0, 0);
            }
        }

        const bool diag = (kt == qt);
        float sv[4][4];
#pragma unroll
        for (int ct = 0; ct < 4; ct++) {
            int col = k0 + ct * 16 + l16;
#pragma unroll
            for (int r = 0; r < 4; r++) {
                float v = s[ct][r] * sscale;
                if (diag) {
                    int row = q0 + wave * 16 + quad * 4 + r;
                    if (col > row) v = -1e30f;
                }
                sv[ct][r] = v;
            }
        }

        float alpha[4];
#pragma unroll
        for (int r = 0; r < 4; r++) {
            float v = fmaxf(fmaxf(sv[0][r], sv[1][r]), fmaxf(sv[2][r], sv[3][r]));
            v = fmaxf(v, __shfl_xor(v, 1));
            v = fmaxf(v, __shfl_xor(v, 2));
            v = fmaxf(v, __shfl_xor(v, 4));
            v = fmaxf(v, __shfl_xor(v, 8));
            float mnew = fmaxf(mrow[r], v);
            alpha[r] = exp2f(mrow[r] - mnew);
            mrow[r]  = mnew;
        }
        // P -> wave-private padded LDS
#pragma unroll
        for (int ct = 0; ct < 4; ct++) {
#pragma unroll
            for (int r = 0; r < 4; r++) {
                float p = exp2f(sv[ct][r] - mrow[r]);
                Ps[wave][(quad * 4 + r) * 72 + ct * 16 + l16] = f2bf(p);
            }
        }
#pragma unroll
        for (int j = 0; j < 8; j++)
#pragma unroll
            for (int r = 0; r < 4; r++) o[j][r] *= alpha[r];
#pragma unroll
        for (int r = 0; r < 4; r++) o9[r] *= alpha[r];

        // PV + row-sum column
#pragma unroll
        for (int kk = 0; kk < 2; kk++) {
            bf16x8 pf = *(const bf16x8*)&Ps[wave][l16 * 72 + kk * 32 + quad * 8];
#pragma unroll
            for (int j = 0; j < 8; j++) {
                bf16x8 vf = *(const bf16x8*)&Vs[(j * 16 + l16) * 72 + kk * 32 + quad * 8];
                o[j] = __builtin_amdgcn_mfma_f32_16x16x32_bf16(pf, vf, o[j], 0, 0, 0);
            }
            o9 = __builtin_amdgcn_mfma_f32_16x16x32_bf16(pf, ones, o9, 0, 0, 0);
        }
    }

    // store partials: Po permuted layout [row][l16][j] -> 16B/lane full-line stores
    const size_t pidx = (size_t)b * NCH + c;
    const size_t pobase = pidx * (64 * 128);
    const size_t mbase  = pidx * 64;
#pragma unroll
    for (int r = 0; r < 4; r++) {
        int row = wave * 16 + quad * 4 + r;
        if (l16 == 0) { Pm[mbase + row] = mrow[r]; Pl[mbase + row] = o9[r]; }
        ushort8 val;
#pragma unroll
        for (int j = 0; j < 8; j++) val[j] = f2bf(o[j][r]);
        *(ushort8*)&Po[pobase + (size_t)row * 128 + l16 * 8] = val;
    }
}

// ---------------------------------------------------------------------------
// Combine n_ch(qt) partials per (b,qt). grid (32, 8, 4), 16 q-rows per block.
// Reads Po in the permuted layout (coalesced), un-permutes on Out write.
// ---------------------------------------------------------------------------
__global__ __launch_bounds__(256)
void combine(const unsigned short* __restrict__ Po, const float* __restrict__ Pm,
             const float* __restrict__ Pl, float* __restrict__ Out)
{
    const int qt = blockIdx.x, b = blockIdx.y, qr = blockIdx.z;  // 16-row quarter
    const int g = qt >> 2;
    const int n_ch = g + 1;
    const int cbase = 2 * g * (g + 1) + (qt - 4 * g) * (g + 1);
    const size_t p0 = (size_t)b * NCH + cbase;
    const int t = threadIdx.x;
    const int p = t & 127;                    // permuted col: p = l16*8 + j
    const int col = (p & 7) * 16 + (p >> 3);  // logical head-dim col
    const int rh = t >> 7;

    __shared__ float sm[8][16], sl[8][16], sw[8][16];
    __shared__ float sinv[16];

    if (t < 128) {
        int s = t >> 4, row = t & 15;
        float mv = -1e30f, lv = 0.0f;
        if (s < n_ch) {
            mv = Pm[(p0 + s) * 64 + qr * 16 + row];
            lv = Pl[(p0 + s) * 64 + qr * 16 + row];
        }
        sm[s][row] = mv; sl[s][row] = lv;
    }
    __syncthreads();
    if (t < 16) {
        int row = t;
        float ms = sm[0][row];
#pragma unroll
        for (int s = 1; s < 8; s++) ms = fmaxf(ms, sm[s][row]);
        float l = 0.0f;
#pragma unroll
        for (int s = 0; s < 8; s++) {
            float w = (sm[s][row] > -1e29f) ? exp2f(sm[s][row] - ms) : 0.0f;
            sw[s][row] = w;
            l += w * sl[s][row];
        }
        sinv[row] = 1.0f / l;
    }
    __syncthreads();

#pragma unroll
    for (int pass = 0; pass < 8; pass++) {
        int row = pass * 2 + rh;          // 0..15 local
        int grow = qr * 16 + row;         // 0..63 within q-tile
        float acc = 0.0f;
#pragma unroll
        for (int s = 0; s < 8; s++) {
            int ss = (s < n_ch) ? s : 0;  // keep load valid; weight is 0
            acc += sw[s][row] * bf2f(Po[(p0 + ss) * 8192 + (size_t)grow * 128 + p]);
        }
        Out[((size_t)b * SS + qt * 64 + grow) * HH + col] = acc * sinv[row];
    }
}

extern "C" void kernel_launch(void* const* d_in, const int* in_sizes, int n_in,
                              void* d_out, int out_size, void* d_ws, size_t ws_size,
                              hipStream_t stream) {
    const float* X    = (const float*)d_in[0];
    const float* mask = (const float*)d_in[1];
    const float* Wq   = (const float*)d_in[2];
    const float* Wk   = (const float*)d_in[3];
    const float* Wv   = (const float*)d_in[4];

    char* ws = (char*)d_ws;
    // region A: Xb (25.2 MB) consumed by qkv_gemm, then reused as Po (18.9 MB)
    unsigned short* Xb = (unsigned short*)ws;
    unsigned short* Po = (unsigned short*)ws;
    ws += (size_t)MM * EE * 2;                                   // 25.17 MB
    unsigned short* Wb = (unsigned short*)ws; ws += (size_t)384 * EE * 2;
    unsigned short* Q  = (unsigned short*)ws; ws += (size_t)MM * HH * 2;
    unsigned short* Kb = (unsigned short*)ws; ws += (size_t)MM * HH * 2;
    unsigned short* Vt = (unsigned short*)ws; ws += (size_t)MM * HH * 2;
    float* Pm = (float*)ws; ws += (size_t)BB * NCH * 64 * 4;
    float* Pl = (float*)ws;

    cvt<<<1536 + 288, 256, 0, stream>>>(X, mask, Wq, Wk, Wv, Xb, Wb);
    qkv_gemm<<<dim3(3, MM / 64), 256, 0, stream>>>(Xb, Wb, Q, Kb, Vt);
    attn<<<dim3(NCH, BB), 256, 0, stream>>>(Q, Kb, Vt, Po, Pm, Pl);
    combine<<<dim3(NQT, BB, 4), 256, 0, stream>>>(Po, Pm, Pl, (float*)d_out);
}